// Round 16
// baseline (137.040 us; speedup 1.0000x reference)
//
#include <hip/hip_runtime.h>
#include <math.h>
#include <float.h>

namespace {

constexpr int kB  = 32;
constexpr int kT  = 4096;
constexpr int kTQ = 64;
constexpr int kD  = 256;
constexpr int kS  = 64;

// Single fused kernel: one block per span (2048 blocks, 256 thr = 4 waves x
// 16 tokens).  qpool fused (L2-hot).  Last block per batch (device-scope
// atomic counter) finalizes the row.
//
// r13/r15 lesson: __launch_bounds__'s 2nd arg is a MINIMUM-occupancy floor;
// the allocator still chose 48 VGPRs + spill of dv[16] (213 us dispatches).
// amdgpu_waves_per_eu(4,4) pins min AND max -> register budget 512/4 = 128
// VGPRs -> no spill.  Body bit-identical to r15 (absmax-validated twice).
__global__ __launch_bounds__(256)
__attribute__((amdgpu_waves_per_eu(4, 4)))
void span_kernel(
    const float* __restrict__ doc, const float* __restrict__ q,
    const float* __restrict__ mask, const float* __restrict__ sscore,
    float* __restrict__ P, float* __restrict__ stm, float* __restrict__ stse,
    unsigned int* __restrict__ cnt) {
  const int blk = blockIdx.x;  // b*kS + s
  const int b = blk >> 6;
  const int tid = threadIdx.x;
  const int wave = tid >> 6;
  const int lane = tid & 63;

  const int myTok = lane >> 2;          // 0..15 within the wave's 16 tokens
  const int t0 = blk * 64 + wave * 16;  // global token base for this wave
  const float* dbase = doc + (size_t)(t0 + myTok) * kD + (lane & 3) * 4;

  // issue ALL 16 doc loads back-to-back (independent of qpool)
  float4 dv[16];
#pragma unroll
  for (int it = 0; it < 16; ++it) {
    dv[it] = *reinterpret_cast<const float4*>(dbase + it * 16);
  }
  const float mk = mask[t0 + myTok];

  // fused qpool: thread tid owns dim tid; 4 independent partial-max chains.
  __shared__ float qpl[kD];
  {
    const float* qb = q + (size_t)b * kTQ * kD + tid;
    float m0 = qb[0 * kD], m1 = qb[16 * kD], m2 = qb[32 * kD], m3 = qb[48 * kD];
#pragma unroll
    for (int k = 1; k < 16; ++k) {
      m0 = fmaxf(m0, qb[(k +  0) * kD]);
      m1 = fmaxf(m1, qb[(k + 16) * kD]);
      m2 = fmaxf(m2, qb[(k + 32) * kD]);
      m3 = fmaxf(m3, qb[(k + 48) * kD]);
    }
    qpl[tid] = fmaxf(fmaxf(m0, m1), fmaxf(m2, m3));
  }
  __syncthreads();

  // compute phase: q from LDS (broadcast ds_read_b128, conflict-free);
  // FMA accumulation order identical to r12.
  const int qoff = (lane & 3) * 4;
  float a0 = 0.f, a1 = 0.f, a2 = 0.f, a3 = 0.f;
#pragma unroll
  for (int it = 0; it < 16; it += 4) {
    const float4 q0 = *reinterpret_cast<const float4*>(&qpl[qoff + (it + 0) * 16]);
    const float4 q1 = *reinterpret_cast<const float4*>(&qpl[qoff + (it + 1) * 16]);
    const float4 q2 = *reinterpret_cast<const float4*>(&qpl[qoff + (it + 2) * 16]);
    const float4 q3 = *reinterpret_cast<const float4*>(&qpl[qoff + (it + 3) * 16]);
    a0 += dv[it + 0].x * q0.x + dv[it + 0].y * q0.y + dv[it + 0].z * q0.z + dv[it + 0].w * q0.w;
    a1 += dv[it + 1].x * q1.x + dv[it + 1].y * q1.y + dv[it + 1].z * q1.z + dv[it + 1].w * q1.w;
    a2 += dv[it + 2].x * q2.x + dv[it + 2].y * q2.y + dv[it + 2].z * q2.z + dv[it + 2].w * q2.w;
    a3 += dv[it + 3].x * q3.x + dv[it + 3].y * q3.y + dv[it + 3].z * q3.z + dv[it + 3].w * q3.w;
  }
  float acc = (a0 + a1) + (a2 + a3);
  acc += __shfl_xor(acc, 1, 64);
  acc += __shfl_xor(acc, 2, 64);

  const float v = (mk != 0.f) ? acc : -INFINITY;

  // span max: butterfly over wave (values 4-replicated; max unaffected)
  float wm = v;
#pragma unroll
  for (int off = 32; off >= 1; off >>= 1) wm = fmaxf(wm, __shfl_xor(wm, off, 64));
  __shared__ float smax[4], ssum[4];
  if (lane == 0) smax[wave] = wm;
  __syncthreads();
  const float m_s = fmaxf(fmaxf(smax[0], smax[1]), fmaxf(smax[2], smax[3]));

  const float e = (v == -INFINITY) ? 0.f : expf(v - m_s);
  float ws = e;
#pragma unroll
  for (int off = 32; off >= 1; off >>= 1) ws += __shfl_xor(ws, off, 64);
  if (lane == 0) ssum[wave] = ws * 0.25f;
  __syncthreads();

  if ((lane & 3) == 0) P[t0 + myTok] = e;
  if (tid == 0) {
    stm[blk] = m_s;
    stse[blk] = (ssum[0] + ssum[1]) + (ssum[2] + ssum[3]);
  }

  // ---- last-block-per-batch finalize ----
  __syncthreads();
  __shared__ unsigned int lastflag;
  if (tid == 0) {
    __threadfence();  // release: this block's P/stm/stse visible device-wide
    const unsigned int old = atomicAdd(&cnt[b], 1u);
    lastflag = (old == (unsigned)(kS - 1)) ? 1u : 0u;
  }
  __syncthreads();
  if (lastflag == 0u) return;

  __threadfence();  // acquire before cross-XCD re-reads

  // wave-parallel redundant stats: lane == span; no LDS round-trip.
  {
    const float m  = __hip_atomic_load(&stm[b * kS + lane], __ATOMIC_RELAXED,
                                       __HIP_MEMORY_SCOPE_AGENT);
    const float se = __hip_atomic_load(&stse[b * kS + lane], __ATOMIC_RELAXED,
                                       __HIP_MEMORY_SCOPE_AGENT);
    const bool mv = se > 0.f;
    float g = mv ? m : -INFINITY;
#pragma unroll
    for (int off = 32; off >= 1; off >>= 1) g = fmaxf(g, __shfl_xor(g, off, 64));
    float den = mv ? expf(m - g) * se : 0.f;
#pragma unroll
    for (int off = 32; off >= 1; off >>= 1) den += __shfl_xor(den, off, 64);
    const float logden = logf(den);

    const float t1 = mv ? expf((m - g) - logden) : 0.f;
    const float sm = (t1 * se) * (1.f / 64.f);
    const bool alive = mv && (sm >= FLT_MIN);  // subnormal/0 -> FTZ dead

    const float s0 = sscore[b * kS + lane];
    float ssv = alive ? s0 : 0.f;
#pragma unroll
    for (int off = 32; off >= 1; off >>= 1) ssv += __shfl_xor(ssv, off, 64);
    const float w = alive ? s0 / (se * ssv) : 0.f;

    // rescale the row: wave handles span (wave + 4j) at step j; the span
    // weight is wave-uniform -> one broadcast shfl per step.
    float* op = P + (size_t)b * kT;
#pragma unroll
    for (int j = 0; j < 16; ++j) {
      const int t = tid + 256 * j;
      const float wmy = __shfl(w, wave + 4 * j, 64);
      const float p = __hip_atomic_load(&op[t], __ATOMIC_RELAXED,
                                        __HIP_MEMORY_SCOPE_AGENT);
      op[t] = p * wmy;
    }
  }
}

}  // namespace

extern "C" void kernel_launch(void* const* d_in, const int* in_sizes, int n_in,
                              void* d_out, int out_size, void* d_ws, size_t ws_size,
                              hipStream_t stream) {
  const float* doc    = (const float*)d_in[0];  // [B,T,D]
  const float* q      = (const float*)d_in[1];  // [B,TQ,D]
  const float* mask   = (const float*)d_in[2];  // [B,T]
  // d_in[3]: spans — deterministic [s*64, s*64+64), unused
  const float* sscore = (const float*)d_in[4];  // [B,S]
  float* out = (float*)d_out;                   // [B,T]

  float* stm  = (float*)d_ws;            // 2048 floats = 8 KB
  float* stse = stm + kB * kS;           // 2048 floats = 8 KB
  unsigned int* cnt = (unsigned int*)(stse + kB * kS);  // 32 u32 = 128 B

  hipMemsetAsync(cnt, 0, kB * sizeof(unsigned int), stream);
  span_kernel<<<kB * kS, 256, 0, stream>>>(doc, q, mask, sscore, out, stm,
                                           stse, cnt);
}

// Round 17
// 30.358 us; speedup vs baseline: 4.5141x; 4.5141x over previous
//
#include <hip/hip_runtime.h>
#include <math.h>
#include <float.h>

namespace {

constexpr int kB  = 32;
constexpr int kT  = 4096;
constexpr int kTQ = 64;
constexpr int kD  = 256;
constexpr int kS  = 64;

// K1: one block per span (2048 blocks, 256 thr = 4 waves x 16 tokens).
// qpool FUSED (block recomputes qp[b,:] from q, L2-hot; doc loads issued
// first so q reads hide under the doc HBM stream).  Identical to round 12.
__global__ __launch_bounds__(256) void span_kernel(const float* __restrict__ doc,
                                                   const float* __restrict__ q,
                                                   const float* __restrict__ mask,
                                                   float* __restrict__ P,
                                                   float* __restrict__ stm,
                                                   float* __restrict__ stse) {
  const int blk = blockIdx.x;  // b*kS + s
  const int b = blk >> 6;
  const int tid = threadIdx.x;
  const int wave = tid >> 6;
  const int lane = tid & 63;

  const int myTok = lane >> 2;          // 0..15 within the wave's 16 tokens
  const int t0 = blk * 64 + wave * 16;  // global token base for this wave
  const float* dbase = doc + (size_t)(t0 + myTok) * kD + (lane & 3) * 4;

  // issue ALL 16 doc loads back-to-back (independent of qpool)
  float4 dv[16];
#pragma unroll
  for (int it = 0; it < 16; ++it) {
    dv[it] = *reinterpret_cast<const float4*>(dbase + it * 16);
  }
  const float mk = mask[t0 + myTok];

  // fused qpool: thread tid owns dim tid; 4 independent partial-max chains.
  __shared__ float qpl[kD];
  {
    const float* qb = q + (size_t)b * kTQ * kD + tid;
    float m0 = qb[0 * kD], m1 = qb[16 * kD], m2 = qb[32 * kD], m3 = qb[48 * kD];
#pragma unroll
    for (int k = 1; k < 16; ++k) {
      m0 = fmaxf(m0, qb[(k +  0) * kD]);
      m1 = fmaxf(m1, qb[(k + 16) * kD]);
      m2 = fmaxf(m2, qb[(k + 32) * kD]);
      m3 = fmaxf(m3, qb[(k + 48) * kD]);
    }
    qpl[tid] = fmaxf(fmaxf(m0, m1), fmaxf(m2, m3));
  }
  __syncthreads();

  // compute phase: q from LDS (broadcast ds_read_b128, conflict-free);
  // FMA accumulation order identical to r12.
  const int qoff = (lane & 3) * 4;
  float a0 = 0.f, a1 = 0.f, a2 = 0.f, a3 = 0.f;
#pragma unroll
  for (int it = 0; it < 16; it += 4) {
    const float4 q0 = *reinterpret_cast<const float4*>(&qpl[qoff + (it + 0) * 16]);
    const float4 q1 = *reinterpret_cast<const float4*>(&qpl[qoff + (it + 1) * 16]);
    const float4 q2 = *reinterpret_cast<const float4*>(&qpl[qoff + (it + 2) * 16]);
    const float4 q3 = *reinterpret_cast<const float4*>(&qpl[qoff + (it + 3) * 16]);
    a0 += dv[it + 0].x * q0.x + dv[it + 0].y * q0.y + dv[it + 0].z * q0.z + dv[it + 0].w * q0.w;
    a1 += dv[it + 1].x * q1.x + dv[it + 1].y * q1.y + dv[it + 1].z * q1.z + dv[it + 1].w * q1.w;
    a2 += dv[it + 2].x * q2.x + dv[it + 2].y * q2.y + dv[it + 2].z * q2.z + dv[it + 2].w * q2.w;
    a3 += dv[it + 3].x * q3.x + dv[it + 3].y * q3.y + dv[it + 3].z * q3.z + dv[it + 3].w * q3.w;
  }
  float acc = (a0 + a1) + (a2 + a3);
  // finish the dot across the 4-lane group (result replicated in all 4 lanes)
  acc += __shfl_xor(acc, 1, 64);
  acc += __shfl_xor(acc, 2, 64);

  const float v = (mk != 0.f) ? acc : -INFINITY;

  // span max: butterfly over wave (values 4-replicated; max unaffected)
  float wm = v;
#pragma unroll
  for (int off = 32; off >= 1; off >>= 1) wm = fmaxf(wm, __shfl_xor(wm, off, 64));
  __shared__ float smax[4], ssum[4];
  if (lane == 0) smax[wave] = wm;
  __syncthreads();
  const float m_s = fmaxf(fmaxf(smax[0], smax[1]), fmaxf(smax[2], smax[3]));

  // e = exp(v - m_s) (0 for masked / fully-masked span); wave sum counts each
  // token 4x -> x0.25 is exact (pure power-of-two scaling).
  const float e = (v == -INFINITY) ? 0.f : expf(v - m_s);
  float ws = e;
#pragma unroll
  for (int off = 32; off >= 1; off >>= 1) ws += __shfl_xor(ws, off, 64);
  if (lane == 0) ssum[wave] = ws * 0.25f;
  __syncthreads();

  if ((lane & 3) == 0) P[t0 + myTok] = e;
  if (tid == 0) {
    stm[blk] = m_s;
    stse[blk] = (ssum[0] + ssum[1]) + (ssum[2] + ssum[3]);
  }
}

// K2: finalize, latency-optimized.  128 blocks (4 per batch row).
// Each thread's P float4 load is issued FIRST (hides under the stats chain);
// every wave redundantly computes all-64-span weights with lane == span
// (butterfly math bit-identical to r12's wave0 path); the needed weight is
// fetched with one __shfl.  No LDS, no __syncthreads.
__global__ __launch_bounds__(256) void fin_kernel(const float* __restrict__ sscore,
                                                  const float* __restrict__ stm,
                                                  const float* __restrict__ stse,
                                                  float* __restrict__ out) {
  const int blk = blockIdx.x;
  const int b = blk >> 2;
  const int qtr = blk & 3;
  const int tid = threadIdx.x;
  const int lane = tid & 63;

  // issue the P load first; consumed only at the very end.
  float* op = out + (size_t)b * kT;
  const int i4 = qtr * 256 + tid;  // float4 index in [0,1024)
  float4 p = reinterpret_cast<float4*>(op)[i4];

  // per-wave redundant span stats: lane == span
  const float m  = stm[b * kS + lane];
  const float se = stse[b * kS + lane];
  const bool mv = se > 0.f;  // span has >=1 unmasked token
  float g = mv ? m : -INFINITY;
#pragma unroll
  for (int off = 32; off >= 1; off >>= 1) g = fmaxf(g, __shfl_xor(g, off, 64));
  float den = mv ? expf(m - g) * se : 0.f;
#pragma unroll
  for (int off = 32; off >= 1; off >>= 1) den += __shfl_xor(den, off, 64);
  const float logden = logf(den);

  const float t1 = mv ? expf((m - g) - logden) : 0.f;
  const float span_sum = t1 * se;
  const float sm = span_sum * (1.f / 64.f);
  const bool alive = mv && (sm >= FLT_MIN);  // subnormal/0 -> FTZ dead

  const float s0 = sscore[b * kS + lane];
  float ssv = alive ? s0 : 0.f;
#pragma unroll
  for (int off = 32; off >= 1; off >>= 1) ssv += __shfl_xor(ssv, off, 64);
  const float w = alive ? s0 / (se * ssv) : 0.f;

  // fetch this thread's span weight (span index i4>>4 in [0,64))
  const float wmy = __shfl(w, i4 >> 4, 64);
  p.x *= wmy; p.y *= wmy; p.z *= wmy; p.w *= wmy;
  reinterpret_cast<float4*>(op)[i4] = p;
}

}  // namespace

extern "C" void kernel_launch(void* const* d_in, const int* in_sizes, int n_in,
                              void* d_out, int out_size, void* d_ws, size_t ws_size,
                              hipStream_t stream) {
  const float* doc    = (const float*)d_in[0];  // [B,T,D]
  const float* q      = (const float*)d_in[1];  // [B,TQ,D]
  const float* mask   = (const float*)d_in[2];  // [B,T]
  // d_in[3]: spans — deterministic [s*64, s*64+64), unused
  const float* sscore = (const float*)d_in[4];  // [B,S]
  float* out = (float*)d_out;                   // [B,T]

  float* stm  = (float*)d_ws;   // 2048 floats = 8 KB
  float* stse = stm + kB * kS;  // 2048 floats = 8 KB

  span_kernel<<<kB * kS, 256, 0, stream>>>(doc, q, mask, out, stm, stse);
  fin_kernel<<<kB * 4, 256, 0, stream>>>(sscore, stm, stse, out);
}